// Round 4
// baseline (1412.406 us; speedup 1.0000x reference)
//
#include <hip/hip_runtime.h>
#include <hip/hip_bf16.h>
#include <stdint.h>

#define NTOK 4096
#define DIM  1024
#define TOPK 128
#define GBLK 32      // blocks in greedy kernel (all co-resident: 32 << 256 CUs)
#define COLS 128     // token columns per greedy block (GBLK*COLS == NTOK)
#define NEGM -1e30f

// ---------------------------------------------------------------------------
// k_prep: rel[n] = ((-a[n]) - min(-a) + 1e-6) / (max(-a) - min(-a))
// ---------------------------------------------------------------------------
__global__ __launch_bounds__(1024) void k_prep(const float* __restrict__ attn,
                                               float* __restrict__ rel) {
  __shared__ float smx[16], smn[16];
  int tid = threadIdx.x;
  float mx = -3.4e38f, mn = 3.4e38f;
  for (int n = tid; n < NTOK; n += 1024) {
    float a = attn[n];
    mx = fmaxf(mx, a); mn = fminf(mn, a);
  }
  for (int o = 32; o >= 1; o >>= 1) {
    mx = fmaxf(mx, __shfl_down(mx, o, 64));
    mn = fminf(mn, __shfl_down(mn, o, 64));
  }
  if ((tid & 63) == 0) { smx[tid >> 6] = mx; smn[tid >> 6] = mn; }
  __syncthreads();
  if (tid == 0) {
    float MX = smx[0], MN = smn[0];
    for (int w = 1; w < 16; ++w) { MX = fmaxf(MX, smx[w]); MN = fminf(MN, smn[w]); }
    smx[0] = MX; smn[0] = MN;
  }
  __syncthreads();
  float amax = smx[0], amin = smn[0];
  float rmin  = -amax;               // min of (-a)
  float range = (-amin) - rmin;      // max - min
  for (int n = tid; n < NTOK; n += 1024) {
    float r = -attn[n];
    rel[n] = ((r - rmin) + 1e-6f) / range;   // same op order as numpy
  }
}

// ---------------------------------------------------------------------------
// k_norm: xn[row] = x[row] / ||x[row]||   (one block per row, fp32)
// ---------------------------------------------------------------------------
__global__ __launch_bounds__(256) void k_norm(const float* __restrict__ x,
                                              float* __restrict__ xn) {
  __shared__ float ps[4];
  int row = blockIdx.x, tid = threadIdx.x;
  const float4* xr = (const float4*)(x + (size_t)row * DIM);
  float4 v = xr[tid];                           // 256 threads * 4 = 1024 elems
  float s = v.x * v.x + v.y * v.y + v.z * v.z + v.w * v.w;
  for (int o = 32; o >= 1; o >>= 1) s += __shfl_down(s, o, 64);
  if ((tid & 63) == 0) ps[tid >> 6] = s;
  __syncthreads();
  if (tid == 0) ps[0] = ps[0] + ps[1] + ps[2] + ps[3];
  __syncthreads();
  float nrm = sqrtf(ps[0]);                      // IEEE sqrt, then IEEE divide
  float4 o4;
  o4.x = v.x / nrm; o4.y = v.y / nrm; o4.z = v.z / nrm; o4.w = v.w / nrm;
  ((float4*)(xn + (size_t)row * DIM))[tid] = o4;
}

// ---------------------------------------------------------------------------
// k_gemm: ker[i][j] = rel[i] * (xn_i . xn_j) * rel[j], fp32, symmetric.
// 128x128 tile per block (256 thr, 8x8 microtile), BK=8, k-major LDS tiles.
// Upper-triangle tiles only. Off-diag lower half written via LDS transpose
// (coalesced float4, bitwise-exact (s*relc)*relr values). Diagonal tiles
// write the full 128x128 block directly (exact for both halves).
// ---------------------------------------------------------------------------
#define BK2 8
__global__ __launch_bounds__(256) void k_gemm(const float* __restrict__ xn,
                                              const float* __restrict__ rel,
                                              float* __restrict__ ker) {
  int bi = blockIdx.y, bj = blockIdx.x;
  if (bi > bj) return;                        // symmetric: skip lower tiles
  __shared__ __align__(16) float As[BK2][132];  // [k][row]
  __shared__ __align__(16) float Bs[BK2][132];
  __shared__ __align__(16) float tr[128][132];  // transpose staging, 67.6 KB
  int tid = threadIdx.x;
  int tx = tid & 15, ty = tid >> 4;           // 16x16 threads, 8x8 micro
  int lrow = tid >> 1, lk = (tid & 1) * 4;    // 128 rows x 2 k-halves
  const float* Ag = xn + (size_t)(bi * 128 + lrow) * DIM + lk;
  const float* Bg = xn + (size_t)(bj * 128 + lrow) * DIM + lk;
  float acc[8][8] = {};
  for (int kt = 0; kt < DIM; kt += BK2) {
    float4 a4 = *(const float4*)(Ag + kt);
    float4 b4 = *(const float4*)(Bg + kt);
    __syncthreads();
    As[lk + 0][lrow] = a4.x; As[lk + 1][lrow] = a4.y;
    As[lk + 2][lrow] = a4.z; As[lk + 3][lrow] = a4.w;
    Bs[lk + 0][lrow] = b4.x; Bs[lk + 1][lrow] = b4.y;
    Bs[lk + 2][lrow] = b4.z; Bs[lk + 3][lrow] = b4.w;
    __syncthreads();
#pragma unroll
    for (int k = 0; k < BK2; ++k) {
      float4 a0 = *(const float4*)&As[k][ty * 8];
      float4 a1 = *(const float4*)&As[k][ty * 8 + 4];
      float4 b0 = *(const float4*)&Bs[k][tx * 8];
      float4 b1 = *(const float4*)&Bs[k][tx * 8 + 4];
      float ar[8] = {a0.x, a0.y, a0.z, a0.w, a1.x, a1.y, a1.z, a1.w};
      float br[8] = {b0.x, b0.y, b0.z, b0.w, b1.x, b1.y, b1.z, b1.w};
#pragma unroll
      for (int r = 0; r < 8; ++r)
#pragma unroll
        for (int c = 0; c < 8; ++c) acc[r][c] += ar[r] * br[c];
    }
  }
  float relr[8], relc[8];
#pragma unroll
  for (int r = 0; r < 8; ++r) relr[r] = rel[bi * 128 + ty * 8 + r];
#pragma unroll
  for (int c = 0; c < 8; ++c) relc[c] = rel[bj * 128 + tx * 8 + c];
#pragma unroll
  for (int r = 0; r < 8; ++r) {
    int gr = bi * 128 + ty * 8 + r;
    // upper half (and full diag tile): (acc*relr)*relc, reference op order
    float4 s0, s1;
    s0.x = (acc[r][0] * relr[r]) * relc[0]; s0.y = (acc[r][1] * relr[r]) * relc[1];
    s0.z = (acc[r][2] * relr[r]) * relc[2]; s0.w = (acc[r][3] * relr[r]) * relc[3];
    s1.x = (acc[r][4] * relr[r]) * relc[4]; s1.y = (acc[r][5] * relr[r]) * relc[5];
    s1.z = (acc[r][6] * relr[r]) * relc[6]; s1.w = (acc[r][7] * relr[r]) * relc[7];
    *(float4*)&ker[(size_t)gr * NTOK + bj * 128 + tx * 8]     = s0;
    *(float4*)&ker[(size_t)gr * NTOK + bj * 128 + tx * 8 + 4] = s1;
  }
  if (bi != bj) {
    // stage lower values (row gc = bj-range, col gr = bi-range) transposed
    __syncthreads();
#pragma unroll
    for (int r = 0; r < 8; ++r)
#pragma unroll
      for (int c = 0; c < 8; ++c)
        tr[tx * 8 + c][ty * 8 + r] = (acc[r][c] * relc[c]) * relr[r];
    __syncthreads();
    int row = tid >> 1, half = tid & 1;     // 128 rows x 2 halves of 64
    float* dst = &ker[(size_t)(bj * 128 + row) * NTOK + bi * 128 + half * 64];
    const float* srcr = &tr[row][half * 64];
#pragma unroll
    for (int e = 0; e < 16; ++e)
      *(float4*)&dst[e * 4] = *(const float4*)&srcr[e * 4];
  }
}

// ---------------------------------------------------------------------------
// k_greedy: 128-step greedy DPP MAP. One token column per thread.
// Per iter: local argmax -> release own candidate slot -> poll 32 slots
// (lanes<32, relaxed + one acquire fence per round, shared via LDS);
// as candidates arrive, PREFETCH ker[c][own slice] + cisT column c for every
// candidate that improves the running max (the winner is always fetched, and
// almost always before the last straggler lands -> dependent fetch hidden).
// cisl is t-major: cisl[t][tid] is thread-private (no conflicts, no races).
// ---------------------------------------------------------------------------
__global__ __launch_bounds__(128) void k_greedy(const float* __restrict__ ker,
                                                const float* __restrict__ feat,
                                                float* __restrict__ out,
                                                float* __restrict__ cisT,
                                                unsigned long long* __restrict__ slots) {
  __shared__ float cisl[TOPK][COLS];            // [t][token], 64 KB
  __shared__ float colcand[GBLK][TOPK];         // candidate columns, 16 KB
  __shared__ unsigned long long candk[GBLK];
  __shared__ unsigned long long red2[2];
  __shared__ unsigned smask;
  __shared__ int selj[TOPK];
  int tid = threadIdx.x;
  int blk = blockIdx.x;
  int n = blk * COLS + tid;                     // this thread's token
  float di2s = ker[(size_t)n * NTOK + n];       // diag of kernel

  for (int i = 0; i < TOPK; ++i) {
    // ---- local argmax (monotonic float->uint key, first-index tie-break)
    unsigned u = __float_as_uint(di2s);
    unsigned key = (u & 0x80000000u) ? ~u : (u | 0x80000000u);
    unsigned long long pk =
        ((unsigned long long)key << 32) | (unsigned)(NTOK - 1 - n);
    for (int o = 32; o >= 1; o >>= 1) {
      unsigned long long q = __shfl_down(pk, o, 64);
      if (q > pk) pk = q;
    }
    if ((tid & 63) == 0) red2[tid >> 6] = pk;
    __syncthreads();   // also drains all lanes' iter-(i-1) cisT stores
    if (tid == 0) {
      unsigned long long m = red2[0] > red2[1] ? red2[0] : red2[1];
      // release: publishes this block's iter-(i-1) cisT stores + candidate
      __hip_atomic_store(&slots[(size_t)i * GBLK + blk], m, __ATOMIC_RELEASE,
                         __HIP_MEMORY_SCOPE_AGENT);
    }
    // ---- poll + prefetch-on-improvement
    unsigned long long best = 0;
    int bestg = 0;
    float kr[GBLK] = {};
    unsigned arrived = 0;
    while (arrived != 0xffffffffu) {
      unsigned long long v = 0;
      if (tid < GBLK && !((arrived >> tid) & 1u))
        v = __hip_atomic_load(&slots[(size_t)i * GBLK + tid], __ATOMIC_RELAXED,
                              __HIP_MEMORY_SCOPE_AGENT);
      if (tid < GBLK && v != 0) candk[tid] = v;
      unsigned long long bal = __ballot(v != 0);   // wave0 bits 0..31; wave1=0
      if (tid == 0) smask = (unsigned)(bal & 0xffffffffu);
      __syncthreads();
      unsigned newm = smask;
      if (newm) {
        __builtin_amdgcn_fence(__ATOMIC_ACQUIRE, "agent");
#pragma unroll
        for (int g = 0; g < GBLK; ++g) {
          if ((newm >> g) & 1u) {
            unsigned long long kv = candk[g];
            if (kv > best) {
              best = kv; bestg = g;
              int cg = NTOK - 1 - (int)(kv & 0xffffffffu);
              kr[g] = ker[(size_t)cg * NTOK + n];          // plain, read-only
              if (tid < i)
                colcand[g][tid] =
                    __hip_atomic_load(&cisT[(size_t)cg * TOPK + tid],
                                      __ATOMIC_RELAXED, __HIP_MEMORY_SCOPE_AGENT);
            }
          }
        }
        arrived |= newm;
      }
      __syncthreads();   // protect candk/smask reuse next round
    }
    // all threads folded the same arrival sets -> same best/bestg everywhere
    int j = NTOK - 1 - (int)(best & 0xffffffffu);
    unsigned kw = (unsigned)(best >> 32);
    unsigned du = (kw & 0x80000000u) ? (kw & 0x7fffffffu) : ~kw;
    float sd = sqrtf(__uint_as_float(du));      // sqrt(di2s[j]) pre-update
    if (tid == 0) selj[i] = j;
    float kj = 0.f;
#pragma unroll
    for (int g = 0; g < GBLK; ++g) if (g == bestg) kj = kr[g];
    // ---- rank-i projection: colcand broadcast, cisl thread-private b32
    float proj = 0.f;
    {
      int t = 0;
      for (; t + 4 <= i; t += 4) {
        proj += colcand[bestg][t]     * cisl[t][tid];
        proj += colcand[bestg][t + 1] * cisl[t + 1][tid];
        proj += colcand[bestg][t + 2] * cisl[t + 2][tid];
        proj += colcand[bestg][t + 3] * cisl[t + 3][tid];
      }
      for (; t < i; ++t) proj += colcand[bestg][t] * cisl[t][tid];
    }
    float eis = (kj - proj) / sd;
    // agent-scope store: published to other XCDs by next iter's release
    __hip_atomic_store(&cisT[(size_t)n * TOPK + i], eis, __ATOMIC_RELAXED,
                       __HIP_MEMORY_SCOPE_AGENT);
    cisl[i][tid] = eis;                         // thread-private history
    di2s -= eis * eis;                          // reference updates all n first,
    if (n == j) di2s = NEGM;                    // then masks j
  }
  __syncthreads();
  // ---- gather output rows: block b copies rows k = b, b+GBLK, ...
  for (int k = blk; k < TOPK; k += GBLK) {
    int j = selj[k];
    const float4* src = (const float4*)(feat + (size_t)j * DIM);
    float4* dst = (float4*)(out + (size_t)k * DIM);
    for (int e = tid; e < DIM / 4; e += COLS) dst[e] = src[e];
  }
}

// ---------------------------------------------------------------------------
// ws layout (bytes):
//   [256,33024)   128*32 u64 candidate slots (zeroed each launch)
//   [49152,65536) rel : 4096 f32
//   [65536,...)   xn  : 4096*1024 f32 (16 MB) -- reused as cisT (4096x128 f32)
//                       after gemm completes (stream-ordered, xn dead then)
//   [65536+16MB)  ker : 4096*4096 f32 (64 MB)
// total ~80.1 MB
// ---------------------------------------------------------------------------
extern "C" void kernel_launch(void* const* d_in, const int* in_sizes, int n_in,
                              void* d_out, int out_size, void* d_ws, size_t ws_size,
                              hipStream_t stream) {
  const float* feat = (const float*)d_in[0];
  const float* attn = (const float*)d_in[1];
  float* out = (float*)d_out;
  char* ws = (char*)d_ws;

  unsigned long long* slots = (unsigned long long*)(ws + 256);
  float* rel = (float*)(ws + 49152);
  float* xn  = (float*)(ws + 65536);
  float* cisT = xn;  // aliases xn: greedy never reads xn, gemm done first
  float* ker = (float*)(ws + 65536 + (size_t)NTOK * DIM * 4);

  hipMemsetAsync(d_ws, 0, 40960, stream);  // zero candidate slots
  k_prep<<<1, 1024, 0, stream>>>(attn, rel);
  k_norm<<<NTOK, 256, 0, stream>>>(feat, xn);
  k_gemm<<<dim3(32, 32), 256, 0, stream>>>(xn, rel, ker);
  k_greedy<<<GBLK, COLS, 0, stream>>>(ker, feat, out, cisT, slots);
}

// Round 5
// 1037.208 us; speedup vs baseline: 1.3617x; 1.3617x over previous
//
#include <hip/hip_runtime.h>
#include <hip/hip_bf16.h>
#include <stdint.h>

#define NTOK 4096
#define DIM  1024
#define TOPK 128
#define GB   8       // greedy blocks (trivially co-resident)
#define GT   512     // threads per greedy block; GB*GT == NTOK, 1 token/thread
#define NEGM -1e30f

// ---------------------------------------------------------------------------
// k_prep: rel[n] = ((-a[n]) - min(-a) + 1e-6) / (max(-a) - min(-a))
// ---------------------------------------------------------------------------
__global__ __launch_bounds__(1024) void k_prep(const float* __restrict__ attn,
                                               float* __restrict__ rel) {
  __shared__ float smx[16], smn[16];
  int tid = threadIdx.x;
  float mx = -3.4e38f, mn = 3.4e38f;
  for (int n = tid; n < NTOK; n += 1024) {
    float a = attn[n];
    mx = fmaxf(mx, a); mn = fminf(mn, a);
  }
  for (int o = 32; o >= 1; o >>= 1) {
    mx = fmaxf(mx, __shfl_down(mx, o, 64));
    mn = fminf(mn, __shfl_down(mn, o, 64));
  }
  if ((tid & 63) == 0) { smx[tid >> 6] = mx; smn[tid >> 6] = mn; }
  __syncthreads();
  if (tid == 0) {
    float MX = smx[0], MN = smn[0];
    for (int w = 1; w < 16; ++w) { MX = fmaxf(MX, smx[w]); MN = fminf(MN, smn[w]); }
    smx[0] = MX; smn[0] = MN;
  }
  __syncthreads();
  float amax = smx[0], amin = smn[0];
  float rmin  = -amax;               // min of (-a)
  float range = (-amin) - rmin;      // max - min
  for (int n = tid; n < NTOK; n += 1024) {
    float r = -attn[n];
    rel[n] = ((r - rmin) + 1e-6f) / range;   // same op order as numpy
  }
}

// ---------------------------------------------------------------------------
// k_norm: xn[row] = x[row] / ||x[row]||   (one block per row, fp32)
// ---------------------------------------------------------------------------
__global__ __launch_bounds__(256) void k_norm(const float* __restrict__ x,
                                              float* __restrict__ xn) {
  __shared__ float ps[4];
  int row = blockIdx.x, tid = threadIdx.x;
  const float4* xr = (const float4*)(x + (size_t)row * DIM);
  float4 v = xr[tid];                           // 256 threads * 4 = 1024 elems
  float s = v.x * v.x + v.y * v.y + v.z * v.z + v.w * v.w;
  for (int o = 32; o >= 1; o >>= 1) s += __shfl_down(s, o, 64);
  if ((tid & 63) == 0) ps[tid >> 6] = s;
  __syncthreads();
  if (tid == 0) ps[0] = ps[0] + ps[1] + ps[2] + ps[3];
  __syncthreads();
  float nrm = sqrtf(ps[0]);                      // IEEE sqrt, then IEEE divide
  float4 o4;
  o4.x = v.x / nrm; o4.y = v.y / nrm; o4.z = v.z / nrm; o4.w = v.w / nrm;
  ((float4*)(xn + (size_t)row * DIM))[tid] = o4;
}

// ---------------------------------------------------------------------------
// k_gemm: ker[i][j] = rel[i] * (xn_i . xn_j) * rel[j], fp32, symmetric.
// ROUND-2 KNOWN-GOOD CONFIG (measured ~350us): 64x64 tile, 4x4 microtile,
// BK=16, k-major LDS. Upper tiles only; both halves stored (bitwise-equal).
// ---------------------------------------------------------------------------
#define BK 16
__global__ __launch_bounds__(256) void k_gemm(const float* __restrict__ xn,
                                              const float* __restrict__ rel,
                                              float* __restrict__ ker) {
  int bi = blockIdx.y, bj = blockIdx.x;
  if (bi > bj) return;                        // symmetric: skip lower tiles
  __shared__ __align__(16) float As[BK][68];  // [k][row], padded vs bank conflicts
  __shared__ __align__(16) float Bs[BK][68];
  int tid = threadIdx.x;
  int tx = tid & 15, ty = tid >> 4;
  int lrow = tid >> 2, lkq = tid & 3;         // 64 rows x 4 k-quads per tile load
  const float* Ag = xn + ((size_t)(bi * 64 + lrow)) * DIM + lkq * 4;
  const float* Bg = xn + ((size_t)(bj * 64 + lrow)) * DIM + lkq * 4;
  float acc[4][4] = {};
  for (int kt = 0; kt < DIM; kt += BK) {
    float4 a4 = *(const float4*)(Ag + kt);
    float4 b4 = *(const float4*)(Bg + kt);
    __syncthreads();
    As[lkq * 4 + 0][lrow] = a4.x; As[lkq * 4 + 1][lrow] = a4.y;
    As[lkq * 4 + 2][lrow] = a4.z; As[lkq * 4 + 3][lrow] = a4.w;
    Bs[lkq * 4 + 0][lrow] = b4.x; Bs[lkq * 4 + 1][lrow] = b4.y;
    Bs[lkq * 4 + 2][lrow] = b4.z; Bs[lkq * 4 + 3][lrow] = b4.w;
    __syncthreads();
#pragma unroll
    for (int k = 0; k < BK; ++k) {
      float4 av = *(const float4*)&As[k][ty * 4];
      float4 bv = *(const float4*)&Bs[k][tx * 4];
      float a[4] = {av.x, av.y, av.z, av.w};
      float b[4] = {bv.x, bv.y, bv.z, bv.w};
#pragma unroll
      for (int r = 0; r < 4; ++r)
#pragma unroll
        for (int c = 0; c < 4; ++c) acc[r][c] += a[r] * b[c];
    }
  }
  float relr[4], relc[4];
#pragma unroll
  for (int r = 0; r < 4; ++r) relr[r] = rel[bi * 64 + ty * 4 + r];
#pragma unroll
  for (int c = 0; c < 4; ++c) relc[c] = rel[bj * 64 + tx * 4 + c];
#pragma unroll
  for (int r = 0; r < 4; ++r) {
#pragma unroll
    for (int c = 0; c < 4; ++c) {
      int gr = bi * 64 + ty * 4 + r, gc = bj * 64 + tx * 4 + c;
      // ker[n][m] = (rel_n * sim) * rel_m  -- reference's exact op order
      ker[(size_t)gr * NTOK + gc] = (acc[r][c] * relr[r]) * relc[c];
      ker[(size_t)gc * NTOK + gr] = (acc[r][c] * relc[c]) * relr[r];
    }
  }
}

// ---------------------------------------------------------------------------
// k_greedy: 128-step greedy DPP MAP. 8 blocks x 512 threads, 1 token/thread.
// Per-thread cis history lives in 128 VGPRs (fully-unrolled proj; colbuf is
// zero-padded beyond i so no guards needed). Tight distributed 8-slot
// exchange (round-3 style). Exchange yields global top-2; the runner-up's
// ker slice is prefetched into a register at iter end and used next iter
// when it wins (uniform branch) -> HBM fetch off the critical path.
// cis layout [t][n]: stores coalesced; column-j read = 128 parallel lanes.
// ---------------------------------------------------------------------------
__global__ __launch_bounds__(GT) void k_greedy(const float* __restrict__ ker,
                                               const float* __restrict__ feat,
                                               float* __restrict__ out,
                                               float* __restrict__ cis,
                                               unsigned long long* __restrict__ slots) {
  __shared__ __align__(16) float colbuf[TOPK];
  __shared__ unsigned long long redw[GT / 64];
  __shared__ unsigned long long s8[GB];
  __shared__ int selj[TOPK];
  int tid = threadIdx.x;
  int blk = blockIdx.x;
  int n = blk * GT + tid;                       // this thread's token
  float di2s = ker[(size_t)n * NTOK + n];       // diag of kernel
  float hist[TOPK];
#pragma unroll
  for (int t = 0; t < TOPK; ++t) hist[t] = 0.f;
  int rprev = -1;
  float pf = 0.f;

  for (int i = 0; i < TOPK; ++i) {
    // ---- local argmax (monotonic float->uint key, first-index tie-break)
    unsigned u = __float_as_uint(di2s);
    unsigned key = (u & 0x80000000u) ? ~u : (u | 0x80000000u);
    unsigned long long pk =
        ((unsigned long long)key << 32) | (unsigned)(NTOK - 1 - n);
    for (int o = 32; o >= 1; o >>= 1) {
      unsigned long long q = __shfl_down(pk, o, 64);
      if (q > pk) pk = q;
    }
    if ((tid & 63) == 0) redw[tid >> 6] = pk;
    __syncthreads();   // drains this block's iter-(i-1) cis stores (vmcnt 0)
    if (tid == 0) {
      unsigned long long m = redw[0];
#pragma unroll
      for (int w = 1; w < GT / 64; ++w) if (redw[w] > m) m = redw[w];
      // release: publishes this block's iter-(i-1) cis stores + candidate
      __hip_atomic_store(&slots[(size_t)i * GB + blk], m, __ATOMIC_RELEASE,
                         __HIP_MEMORY_SCOPE_AGENT);
    }
    // ---- tight poll of the 8 per-block slots (lanes 0..7 of wave 0)
    if (tid < GB) {
      unsigned long long v;
      do {
        v = __hip_atomic_load(&slots[(size_t)i * GB + tid], __ATOMIC_RELAXED,
                              __HIP_MEMORY_SCOPE_AGENT);
      } while (v == 0);
      s8[tid] = v;
    }
    __syncthreads();
    __builtin_amdgcn_fence(__ATOMIC_ACQUIRE, "agent");  // order cis/ker reads
    // ---- every thread decodes global top-2 from the 8 candidates
    unsigned long long b1 = 0, b2 = 0;
#pragma unroll
    for (int g = 0; g < GB; ++g) {
      unsigned long long x = s8[g];
      if (x > b1) { b2 = b1; b1 = x; }
      else if (x > b2) { b2 = x; }
    }
    int j = NTOK - 1 - (int)(b1 & 0xffffffffu);
    int r = NTOK - 1 - (int)(b2 & 0xffffffffu);
    unsigned kw = (unsigned)(b1 >> 32);
    unsigned du = (kw & 0x80000000u) ? (kw & 0x7fffffffu) : ~kw;
    float sd = sqrtf(__uint_as_float(du));      // sqrt(di2s[j]) pre-update
    if (tid == 0) selj[i] = j;
    // ---- kj: speculation hit -> register; miss -> issue load now (uniform)
    float kj;
    if (j == rprev) kj = pf;
    else            kj = ker[(size_t)j * NTOK + n];   // 2KB/block, coalesced
    // ---- cis column j (t < i), zero-padded to TOPK for guard-free proj
    if (tid < TOPK)
      colbuf[tid] = (tid < i)
          ? __hip_atomic_load(&cis[(size_t)tid * NTOK + j], __ATOMIC_RELAXED,
                              __HIP_MEMORY_SCOPE_AGENT)
          : 0.f;
    __syncthreads();
    // ---- rank-i projection vs register history (32x ds_read_b128 + fma)
    float proj = 0.f;
#pragma unroll
    for (int t = 0; t < TOPK; t += 4) {
      float4 c4 = *(const float4*)&colbuf[t];
      proj += c4.x * hist[t] + c4.y * hist[t + 1] +
              c4.z * hist[t + 2] + c4.w * hist[t + 3];
    }
    float eis = (kj - proj) / sd;
    // agent-scope store: published to other XCDs by next iter's release
    __hip_atomic_store(&cis[(size_t)i * NTOK + n], eis, __ATOMIC_RELAXED,
                       __HIP_MEMORY_SCOPE_AGENT);
#pragma unroll
    for (int t = 0; t < TOPK; ++t) if (t == i) hist[t] = eis;
    di2s -= eis * eis;                          // reference updates all n first,
    if (n == j) di2s = NEGM;                    // then masks j
    // ---- speculative prefetch of runner-up's ker slice (fire-and-forget;
    //      the next __syncthreads drains it, so it's ready if r wins)
    rprev = r;
    pf = ker[(size_t)r * NTOK + n];
    __syncthreads();   // protect s8/colbuf reuse before next round's writes
  }
  // ---- gather output rows: block b copies rows k = b, b+GB, ...
  for (int k = blk; k < TOPK; k += GB) {
    int j = selj[k];
    ((float2*)(out + (size_t)k * DIM))[tid] =
        ((const float2*)(feat + (size_t)j * DIM))[tid];
  }
}

// ---------------------------------------------------------------------------
// ws layout (bytes):
//   [256,8448)    128*8 u64 candidate slots (zeroed each launch)
//   [49152,65536) rel : 4096 f32
//   [65536,...)   xn  : 4096*1024 f32 (16 MB) -- reused as cis (128x4096 f32)
//                       after gemm completes (stream-ordered, xn dead then)
//   [65536+16MB)  ker : 4096*4096 f32 (64 MB)
// total ~80.1 MB
// ---------------------------------------------------------------------------
extern "C" void kernel_launch(void* const* d_in, const int* in_sizes, int n_in,
                              void* d_out, int out_size, void* d_ws, size_t ws_size,
                              hipStream_t stream) {
  const float* feat = (const float*)d_in[0];
  const float* attn = (const float*)d_in[1];
  float* out = (float*)d_out;
  char* ws = (char*)d_ws;

  unsigned long long* slots = (unsigned long long*)(ws + 256);
  float* rel = (float*)(ws + 49152);
  float* xn  = (float*)(ws + 65536);
  float* cis = xn;  // aliases xn: greedy never reads xn, gemm done first
  float* ker = (float*)(ws + 65536 + (size_t)NTOK * DIM * 4);

  hipMemsetAsync(d_ws, 0, 16384, stream);  // zero candidate slots
  k_prep<<<1, 1024, 0, stream>>>(attn, rel);
  k_norm<<<NTOK, 256, 0, stream>>>(feat, xn);
  k_gemm<<<dim3(64, 64), 256, 0, stream>>>(xn, rel, ker);
  k_greedy<<<GB, GT, 0, stream>>>(ker, feat, out, cis, slots);
}

// Round 6
// 899.702 us; speedup vs baseline: 1.5699x; 1.1528x over previous
//
#include <hip/hip_runtime.h>
#include <hip/hip_bf16.h>
#include <stdint.h>

#define NTOK 4096
#define DIM  1024
#define TOPK 128
#define GB   16      // greedy blocks (trivially co-resident on 256 CUs)
#define GT   256     // threads per greedy block; GB*GT == NTOK, 1 token/thread
#define NEGM -1e30f

// ---------------------------------------------------------------------------
// k_prep: rel[n] = ((-a[n]) - min(-a) + 1e-6) / (max(-a) - min(-a))
// ---------------------------------------------------------------------------
__global__ __launch_bounds__(1024) void k_prep(const float* __restrict__ attn,
                                               float* __restrict__ rel) {
  __shared__ float smx[16], smn[16];
  int tid = threadIdx.x;
  float mx = -3.4e38f, mn = 3.4e38f;
  for (int n = tid; n < NTOK; n += 1024) {
    float a = attn[n];
    mx = fmaxf(mx, a); mn = fminf(mn, a);
  }
  for (int o = 32; o >= 1; o >>= 1) {
    mx = fmaxf(mx, __shfl_down(mx, o, 64));
    mn = fminf(mn, __shfl_down(mn, o, 64));
  }
  if ((tid & 63) == 0) { smx[tid >> 6] = mx; smn[tid >> 6] = mn; }
  __syncthreads();
  if (tid == 0) {
    float MX = smx[0], MN = smn[0];
    for (int w = 1; w < 16; ++w) { MX = fmaxf(MX, smx[w]); MN = fminf(MN, smn[w]); }
    smx[0] = MX; smn[0] = MN;
  }
  __syncthreads();
  float amax = smx[0], amin = smn[0];
  float rmin  = -amax;               // min of (-a)
  float range = (-amin) - rmin;      // max - min
  for (int n = tid; n < NTOK; n += 1024) {
    float r = -attn[n];
    rel[n] = ((r - rmin) + 1e-6f) / range;   // same op order as numpy
  }
}

// ---------------------------------------------------------------------------
// k_norm: xn[row] = x[row] / ||x[row]||   (one block per row, fp32)
// ---------------------------------------------------------------------------
__global__ __launch_bounds__(256) void k_norm(const float* __restrict__ x,
                                              float* __restrict__ xn) {
  __shared__ float ps[4];
  int row = blockIdx.x, tid = threadIdx.x;
  const float4* xr = (const float4*)(x + (size_t)row * DIM);
  float4 v = xr[tid];                           // 256 threads * 4 = 1024 elems
  float s = v.x * v.x + v.y * v.y + v.z * v.z + v.w * v.w;
  for (int o = 32; o >= 1; o >>= 1) s += __shfl_down(s, o, 64);
  if ((tid & 63) == 0) ps[tid >> 6] = s;
  __syncthreads();
  if (tid == 0) ps[0] = ps[0] + ps[1] + ps[2] + ps[3];
  __syncthreads();
  float nrm = sqrtf(ps[0]);                      // IEEE sqrt, then IEEE divide
  float4 o4;
  o4.x = v.x / nrm; o4.y = v.y / nrm; o4.z = v.z / nrm; o4.w = v.w / nrm;
  ((float4*)(xn + (size_t)row * DIM))[tid] = o4;
}

// ---------------------------------------------------------------------------
// k_gemm: ker[i][j] = rel[i] * (xn_i . xn_j) * rel[j], fp32, symmetric.
// ROUND-2 KNOWN-GOOD CONFIG (~350us): 64x64 tile, 4x4 microtile, BK=16,
// k-major LDS. Upper tiles only; both halves stored (bitwise-equal).
// ---------------------------------------------------------------------------
#define BK 16
__global__ __launch_bounds__(256) void k_gemm(const float* __restrict__ xn,
                                              const float* __restrict__ rel,
                                              float* __restrict__ ker) {
  int bi = blockIdx.y, bj = blockIdx.x;
  if (bi > bj) return;                        // symmetric: skip lower tiles
  __shared__ __align__(16) float As[BK][68];  // [k][row], padded vs bank conflicts
  __shared__ __align__(16) float Bs[BK][68];
  int tid = threadIdx.x;
  int tx = tid & 15, ty = tid >> 4;
  int lrow = tid >> 2, lkq = tid & 3;         // 64 rows x 4 k-quads per tile load
  const float* Ag = xn + ((size_t)(bi * 64 + lrow)) * DIM + lkq * 4;
  const float* Bg = xn + ((size_t)(bj * 64 + lrow)) * DIM + lkq * 4;
  float acc[4][4] = {};
  for (int kt = 0; kt < DIM; kt += BK) {
    float4 a4 = *(const float4*)(Ag + kt);
    float4 b4 = *(const float4*)(Bg + kt);
    __syncthreads();
    As[lkq * 4 + 0][lrow] = a4.x; As[lkq * 4 + 1][lrow] = a4.y;
    As[lkq * 4 + 2][lrow] = a4.z; As[lkq * 4 + 3][lrow] = a4.w;
    Bs[lkq * 4 + 0][lrow] = b4.x; Bs[lkq * 4 + 1][lrow] = b4.y;
    Bs[lkq * 4 + 2][lrow] = b4.z; Bs[lkq * 4 + 3][lrow] = b4.w;
    __syncthreads();
#pragma unroll
    for (int k = 0; k < BK; ++k) {
      float4 av = *(const float4*)&As[k][ty * 4];
      float4 bv = *(const float4*)&Bs[k][tx * 4];
      float a[4] = {av.x, av.y, av.z, av.w};
      float b[4] = {bv.x, bv.y, bv.z, bv.w};
#pragma unroll
      for (int r = 0; r < 4; ++r)
#pragma unroll
        for (int c = 0; c < 4; ++c) acc[r][c] += a[r] * b[c];
    }
  }
  float relr[4], relc[4];
#pragma unroll
  for (int r = 0; r < 4; ++r) relr[r] = rel[bi * 64 + ty * 4 + r];
#pragma unroll
  for (int c = 0; c < 4; ++c) relc[c] = rel[bj * 64 + tx * 4 + c];
#pragma unroll
  for (int r = 0; r < 4; ++r) {
#pragma unroll
    for (int c = 0; c < 4; ++c) {
      int gr = bi * 64 + ty * 4 + r, gc = bj * 64 + tx * 4 + c;
      // ker[n][m] = (rel_n * sim) * rel_m  -- reference's exact op order
      ker[(size_t)gr * NTOK + gc] = (acc[r][c] * relr[r]) * relc[c];
      ker[(size_t)gc * NTOK + gr] = (acc[r][c] * relc[c]) * relr[r];
    }
  }
}

// ---------------------------------------------------------------------------
// k_greedy: 128-step greedy DPP MAP. 16 blocks x 256 threads, 1 token/thread.
// __launch_bounds__(GT,1) -> 512-VGPR budget so hist[128] stays in registers
// (r5's 512-thread version spilled hist to scratch: VGPR_Count=88, 680us).
// Per iter: block argmax -> release candidate slot -> 16 lanes tight-poll the
// 16 slots -> decode winner everywhere -> kj + cis-column loads issued
// back-to-back (overlapped RTs) -> guard-free unrolled proj vs register hist.
// cis layout [t][n]: stores coalesced; column read = 128 parallel lanes.
// ---------------------------------------------------------------------------
__global__ __launch_bounds__(GT, 1) void k_greedy(const float* __restrict__ ker,
                                                  const float* __restrict__ feat,
                                                  float* __restrict__ out,
                                                  float* __restrict__ cis,
                                                  unsigned long long* __restrict__ slots) {
  __shared__ __align__(16) float colbuf[TOPK];
  __shared__ unsigned long long redw[GT / 64];
  __shared__ unsigned long long s16[GB];
  __shared__ int selj[TOPK];
  int tid = threadIdx.x;
  int blk = blockIdx.x;
  int n = blk * GT + tid;                       // this thread's token
  float di2s = ker[(size_t)n * NTOK + n];       // diag of kernel
  float hist[TOPK];
#pragma unroll
  for (int t = 0; t < TOPK; ++t) hist[t] = 0.f;

  for (int i = 0; i < TOPK; ++i) {
    // ---- local argmax (monotonic float->uint key, first-index tie-break)
    unsigned u = __float_as_uint(di2s);
    unsigned key = (u & 0x80000000u) ? ~u : (u | 0x80000000u);
    unsigned long long pk =
        ((unsigned long long)key << 32) | (unsigned)(NTOK - 1 - n);
    for (int o = 32; o >= 1; o >>= 1) {
      unsigned long long q = __shfl_down(pk, o, 64);
      if (q > pk) pk = q;
    }
    if ((tid & 63) == 0) redw[tid >> 6] = pk;
    __syncthreads();   // drains this block's iter-(i-1) cis stores (vmcnt 0)
    if (tid == 0) {
      unsigned long long m = redw[0];
#pragma unroll
      for (int w = 1; w < GT / 64; ++w) if (redw[w] > m) m = redw[w];
      // release: publishes this block's iter-(i-1) cis stores + candidate
      __hip_atomic_store(&slots[(size_t)i * GB + blk], m, __ATOMIC_RELEASE,
                         __HIP_MEMORY_SCOPE_AGENT);
    }
    // ---- tight poll of the 16 per-block slots (lanes 0..15 of wave 0)
    if (tid < GB) {
      unsigned long long v;
      do {
        v = __hip_atomic_load(&slots[(size_t)i * GB + tid], __ATOMIC_RELAXED,
                              __HIP_MEMORY_SCOPE_AGENT);
      } while (v == 0);
      s16[tid] = v;
    }
    __syncthreads();
    __builtin_amdgcn_fence(__ATOMIC_ACQUIRE, "agent");  // order cis/ker reads
    // ---- every thread decodes the global winner from the 16 candidates
    unsigned long long b1 = 0;
#pragma unroll
    for (int g = 0; g < GB; ++g) {
      unsigned long long x = s16[g];
      if (x > b1) b1 = x;
    }
    int j = NTOK - 1 - (int)(b1 & 0xffffffffu);
    unsigned kw = (unsigned)(b1 >> 32);
    unsigned du = (kw & 0x80000000u) ? (kw & 0x7fffffffu) : ~kw;
    float sd = sqrtf(__uint_as_float(du));      // sqrt(di2s[j]) pre-update
    if (tid == 0) selj[i] = j;
    // ---- both dependent fetches issued back-to-back (latencies overlap):
    float kj = ker[(size_t)j * NTOK + n];       // 1KB/block, coalesced
    if (tid < TOPK)
      colbuf[tid] = (tid < i)
          ? __hip_atomic_load(&cis[(size_t)tid * NTOK + j], __ATOMIC_RELAXED,
                              __HIP_MEMORY_SCOPE_AGENT)
          : 0.f;
    __syncthreads();
    // ---- rank-i projection vs register hist (colbuf zero-padded: no guards)
    float proj = 0.f;
#pragma unroll
    for (int t = 0; t < TOPK; t += 4) {
      float4 c4 = *(const float4*)&colbuf[t];
      proj += c4.x * hist[t] + c4.y * hist[t + 1] +
              c4.z * hist[t + 2] + c4.w * hist[t + 3];
    }
    float eis = (kj - proj) / sd;
    // agent-scope store: published to other XCDs by next iter's release
    __hip_atomic_store(&cis[(size_t)i * NTOK + n], eis, __ATOMIC_RELAXED,
                       __HIP_MEMORY_SCOPE_AGENT);
#pragma unroll
    for (int t = 0; t < TOPK; ++t) if (t == i) hist[t] = eis;
    di2s -= eis * eis;                          // reference updates all n first,
    if (n == j) di2s = NEGM;                    // then masks j
  }
  __syncthreads();
  // ---- gather output rows: block b copies rows k = b, b+GB, ...
  for (int k = blk; k < TOPK; k += GB) {
    int j = selj[k];
    ((float4*)(out + (size_t)k * DIM))[tid] =
        ((const float4*)(feat + (size_t)j * DIM))[tid];
  }
}

// ---------------------------------------------------------------------------
// ws layout (bytes):
//   [256,16640)   128*16 u64 candidate slots (zeroed each launch)
//   [49152,65536) rel : 4096 f32
//   [65536,...)   xn  : 4096*1024 f32 (16 MB) -- reused as cis (128x4096 f32)
//                       after gemm completes (stream-ordered, xn dead then)
//   [65536+16MB)  ker : 4096*4096 f32 (64 MB)
// total ~80.1 MB
// ---------------------------------------------------------------------------
extern "C" void kernel_launch(void* const* d_in, const int* in_sizes, int n_in,
                              void* d_out, int out_size, void* d_ws, size_t ws_size,
                              hipStream_t stream) {
  const float* feat = (const float*)d_in[0];
  const float* attn = (const float*)d_in[1];
  float* out = (float*)d_out;
  char* ws = (char*)d_ws;

  unsigned long long* slots = (unsigned long long*)(ws + 256);
  float* rel = (float*)(ws + 49152);
  float* xn  = (float*)(ws + 65536);
  float* cis = xn;  // aliases xn: greedy never reads xn, gemm done first
  float* ker = (float*)(ws + 65536 + (size_t)NTOK * DIM * 4);

  hipMemsetAsync(d_ws, 0, 32768, stream);  // zero candidate slots
  k_prep<<<1, 1024, 0, stream>>>(attn, rel);
  k_norm<<<NTOK, 256, 0, stream>>>(feat, xn);
  k_gemm<<<dim3(64, 64), 256, 0, stream>>>(xn, rel, ker);
  k_greedy<<<GB, GT, 0, stream>>>(ker, feat, out, cis, slots);
}

// Round 7
// 831.996 us; speedup vs baseline: 1.6976x; 1.0814x over previous
//
#include <hip/hip_runtime.h>
#include <hip/hip_bf16.h>
#include <stdint.h>

#define NTOK 4096
#define DIM  1024
#define TOPK 128
#define GB   16      // greedy blocks (trivially co-resident on 256 CUs)
#define GT   256     // threads per greedy block; GB*GT == NTOK, 1 token/thread
#define NEGM -1e30f

// ---------------------------------------------------------------------------
// k_prep: rel[n] = ((-a[n]) - min(-a) + 1e-6) / (max(-a) - min(-a))
// ---------------------------------------------------------------------------
__global__ __launch_bounds__(1024) void k_prep(const float* __restrict__ attn,
                                               float* __restrict__ rel) {
  __shared__ float smx[16], smn[16];
  int tid = threadIdx.x;
  float mx = -3.4e38f, mn = 3.4e38f;
  for (int n = tid; n < NTOK; n += 1024) {
    float a = attn[n];
    mx = fmaxf(mx, a); mn = fminf(mn, a);
  }
  for (int o = 32; o >= 1; o >>= 1) {
    mx = fmaxf(mx, __shfl_down(mx, o, 64));
    mn = fminf(mn, __shfl_down(mn, o, 64));
  }
  if ((tid & 63) == 0) { smx[tid >> 6] = mx; smn[tid >> 6] = mn; }
  __syncthreads();
  if (tid == 0) {
    float MX = smx[0], MN = smn[0];
    for (int w = 1; w < 16; ++w) { MX = fmaxf(MX, smx[w]); MN = fminf(MN, smn[w]); }
    smx[0] = MX; smn[0] = MN;
  }
  __syncthreads();
  float amax = smx[0], amin = smn[0];
  float rmin  = -amax;               // min of (-a)
  float range = (-amin) - rmin;      // max - min
  for (int n = tid; n < NTOK; n += 1024) {
    float r = -attn[n];
    rel[n] = ((r - rmin) + 1e-6f) / range;   // same op order as numpy
  }
}

// ---------------------------------------------------------------------------
// k_norm: xn[row] = x[row] / ||x[row]||   (one block per row, fp32)
// ---------------------------------------------------------------------------
__global__ __launch_bounds__(256) void k_norm(const float* __restrict__ x,
                                              float* __restrict__ xn) {
  __shared__ float ps[4];
  int row = blockIdx.x, tid = threadIdx.x;
  const float4* xr = (const float4*)(x + (size_t)row * DIM);
  float4 v = xr[tid];                           // 256 threads * 4 = 1024 elems
  float s = v.x * v.x + v.y * v.y + v.z * v.z + v.w * v.w;
  for (int o = 32; o >= 1; o >>= 1) s += __shfl_down(s, o, 64);
  if ((tid & 63) == 0) ps[tid >> 6] = s;
  __syncthreads();
  if (tid == 0) ps[0] = ps[0] + ps[1] + ps[2] + ps[3];
  __syncthreads();
  float nrm = sqrtf(ps[0]);                      // IEEE sqrt, then IEEE divide
  float4 o4;
  o4.x = v.x / nrm; o4.y = v.y / nrm; o4.z = v.z / nrm; o4.w = v.w / nrm;
  ((float4*)(xn + (size_t)row * DIM))[tid] = o4;
}

// ---------------------------------------------------------------------------
// k_gemm: ker[i][j] = rel[i] * (xn_i . xn_j) * rel[j], fp32, symmetric.
// ROUND-2 KNOWN-GOOD CONFIG (~345us): 64x64 tile, 4x4 microtile, BK=16,
// k-major LDS. Upper tiles only; both halves stored (bitwise-equal).
// ---------------------------------------------------------------------------
#define BK 16
__global__ __launch_bounds__(256) void k_gemm(const float* __restrict__ xn,
                                              const float* __restrict__ rel,
                                              float* __restrict__ ker) {
  int bi = blockIdx.y, bj = blockIdx.x;
  if (bi > bj) return;                        // symmetric: skip lower tiles
  __shared__ __align__(16) float As[BK][68];  // [k][row], padded vs bank conflicts
  __shared__ __align__(16) float Bs[BK][68];
  int tid = threadIdx.x;
  int tx = tid & 15, ty = tid >> 4;
  int lrow = tid >> 2, lkq = tid & 3;         // 64 rows x 4 k-quads per tile load
  const float* Ag = xn + ((size_t)(bi * 64 + lrow)) * DIM + lkq * 4;
  const float* Bg = xn + ((size_t)(bj * 64 + lrow)) * DIM + lkq * 4;
  float acc[4][4] = {};
  for (int kt = 0; kt < DIM; kt += BK) {
    float4 a4 = *(const float4*)(Ag + kt);
    float4 b4 = *(const float4*)(Bg + kt);
    __syncthreads();
    As[lkq * 4 + 0][lrow] = a4.x; As[lkq * 4 + 1][lrow] = a4.y;
    As[lkq * 4 + 2][lrow] = a4.z; As[lkq * 4 + 3][lrow] = a4.w;
    Bs[lkq * 4 + 0][lrow] = b4.x; Bs[lkq * 4 + 1][lrow] = b4.y;
    Bs[lkq * 4 + 2][lrow] = b4.z; Bs[lkq * 4 + 3][lrow] = b4.w;
    __syncthreads();
#pragma unroll
    for (int k = 0; k < BK; ++k) {
      float4 av = *(const float4*)&As[k][ty * 4];
      float4 bv = *(const float4*)&Bs[k][tx * 4];
      float a[4] = {av.x, av.y, av.z, av.w};
      float b[4] = {bv.x, bv.y, bv.z, bv.w};
#pragma unroll
      for (int r = 0; r < 4; ++r)
#pragma unroll
        for (int c = 0; c < 4; ++c) acc[r][c] += a[r] * b[c];
    }
  }
  float relr[4], relc[4];
#pragma unroll
  for (int r = 0; r < 4; ++r) relr[r] = rel[bi * 64 + ty * 4 + r];
#pragma unroll
  for (int c = 0; c < 4; ++c) relc[c] = rel[bj * 64 + tx * 4 + c];
#pragma unroll
  for (int r = 0; r < 4; ++r) {
#pragma unroll
    for (int c = 0; c < 4; ++c) {
      int gr = bi * 64 + ty * 4 + r, gc = bj * 64 + tx * 4 + c;
      // ker[n][m] = (rel_n * sim) * rel_m  -- reference's exact op order
      ker[(size_t)gr * NTOK + gc] = (acc[r][c] * relr[r]) * relc[c];
      ker[(size_t)gc * NTOK + gr] = (acc[r][c] * relc[c]) * relr[r];
    }
  }
}

// ---------------------------------------------------------------------------
// k_greedy: 128-step greedy DPP MAP. 16 blocks x 256 threads, 1 token/thread.
// History lives in LDS t-major histL[t][tid] (128 KB): thread-private column,
// consecutive lanes -> 2-way bank aliasing = free. (r5/r6 register-hist
// attempts spilled to scratch: SROA runs before unrolling, so hist[t] with
// loop-variant index is never promoted -- VGPR_Count=88 both rounds.)
// Per iter: block argmax -> release candidate slot -> 16 lanes tight-poll ->
// decode winner -> kj + cis-column fetches back-to-back -> proj from LDS.
// cis layout [t][n]: stores coalesced; column read = 128 parallel lanes.
// ---------------------------------------------------------------------------
__global__ __launch_bounds__(GT) void k_greedy(const float* __restrict__ ker,
                                               const float* __restrict__ feat,
                                               float* __restrict__ out,
                                               float* __restrict__ cis,
                                               unsigned long long* __restrict__ slots) {
  __shared__ float histL[TOPK][GT];             // [t][token], 128 KB
  __shared__ __align__(16) float colbuf[TOPK];
  __shared__ unsigned long long redw[GT / 64];
  __shared__ unsigned long long s16[GB];
  __shared__ int selj[TOPK];
  int tid = threadIdx.x;
  int blk = blockIdx.x;
  int n = blk * GT + tid;                       // this thread's token
  float di2s = ker[(size_t)n * NTOK + n];       // diag of kernel

  for (int i = 0; i < TOPK; ++i) {
    // ---- local argmax (monotonic float->uint key, first-index tie-break)
    unsigned u = __float_as_uint(di2s);
    unsigned key = (u & 0x80000000u) ? ~u : (u | 0x80000000u);
    unsigned long long pk =
        ((unsigned long long)key << 32) | (unsigned)(NTOK - 1 - n);
    for (int o = 32; o >= 1; o >>= 1) {
      unsigned long long q = __shfl_down(pk, o, 64);
      if (q > pk) pk = q;
    }
    if ((tid & 63) == 0) redw[tid >> 6] = pk;
    __syncthreads();   // drains this block's iter-(i-1) cis stores
    if (tid == 0) {
      unsigned long long m = redw[0];
#pragma unroll
      for (int w = 1; w < GT / 64; ++w) if (redw[w] > m) m = redw[w];
      // release: publishes this block's iter-(i-1) cis stores + candidate
      __hip_atomic_store(&slots[(size_t)i * GB + blk], m, __ATOMIC_RELEASE,
                         __HIP_MEMORY_SCOPE_AGENT);
    }
    // ---- tight poll of the 16 per-block slots (lanes 0..15 of wave 0)
    if (tid < GB) {
      unsigned long long v;
      do {
        v = __hip_atomic_load(&slots[(size_t)i * GB + tid], __ATOMIC_RELAXED,
                              __HIP_MEMORY_SCOPE_AGENT);
      } while (v == 0);
      s16[tid] = v;
    }
    __syncthreads();
    __builtin_amdgcn_fence(__ATOMIC_ACQUIRE, "agent");  // order cis/ker reads
    // ---- every thread decodes the global winner from the 16 candidates
    unsigned long long b1 = 0;
#pragma unroll
    for (int g = 0; g < GB; ++g) {
      unsigned long long x = s16[g];
      if (x > b1) b1 = x;
    }
    int j = NTOK - 1 - (int)(b1 & 0xffffffffu);
    unsigned kw = (unsigned)(b1 >> 32);
    unsigned du = (kw & 0x80000000u) ? (kw & 0x7fffffffu) : ~kw;
    float sd = sqrtf(__uint_as_float(du));      // sqrt(di2s[j]) pre-update
    if (tid == 0) selj[i] = j;
    // ---- both dependent fetches issued back-to-back (latencies overlap):
    float kj = ker[(size_t)j * NTOK + n];       // 1KB/block, coalesced
    if (tid < TOPK)
      colbuf[tid] = (tid < i)
          ? __hip_atomic_load(&cis[(size_t)tid * NTOK + j], __ATOMIC_RELAXED,
                              __HIP_MEMORY_SCOPE_AGENT)
          : 0.f;
    __syncthreads();
    // ---- rank-i projection: b128 colbuf broadcast + conflict-free b32 hist
    float proj = 0.f;
#pragma unroll
    for (int t = 0; t < TOPK; t += 4) {
      float4 c4 = *(const float4*)&colbuf[t];
      proj += c4.x * histL[t][tid] + c4.y * histL[t + 1][tid] +
              c4.z * histL[t + 2][tid] + c4.w * histL[t + 3][tid];
    }
    float eis = (kj - proj) / sd;
    // agent-scope store: published to other XCDs by next iter's release
    __hip_atomic_store(&cis[(size_t)i * NTOK + n], eis, __ATOMIC_RELAXED,
                       __HIP_MEMORY_SCOPE_AGENT);
    histL[i][tid] = eis;                        // thread-private column write
    di2s -= eis * eis;                          // reference updates all n first,
    if (n == j) di2s = NEGM;                    // then masks j
  }
  __syncthreads();
  // ---- gather output rows: block b copies rows k = b, b+GB, ...
  for (int k = blk; k < TOPK; k += GB) {
    int j = selj[k];
    ((float4*)(out + (size_t)k * DIM))[tid] =
        ((const float4*)(feat + (size_t)j * DIM))[tid];
  }
}

// ---------------------------------------------------------------------------
// ws layout (bytes):
//   [256,16640)   128*16 u64 candidate slots (zeroed each launch)
//   [49152,65536) rel : 4096 f32
//   [65536,...)   xn  : 4096*1024 f32 (16 MB) -- reused as cis (128x4096 f32)
//                       after gemm completes (stream-ordered, xn dead then)
//   [65536+16MB)  ker : 4096*4096 f32 (64 MB)
// total ~80.1 MB
// ---------------------------------------------------------------------------
extern "C" void kernel_launch(void* const* d_in, const int* in_sizes, int n_in,
                              void* d_out, int out_size, void* d_ws, size_t ws_size,
                              hipStream_t stream) {
  const float* feat = (const float*)d_in[0];
  const float* attn = (const float*)d_in[1];
  float* out = (float*)d_out;
  char* ws = (char*)d_ws;

  unsigned long long* slots = (unsigned long long*)(ws + 256);
  float* rel = (float*)(ws + 49152);
  float* xn  = (float*)(ws + 65536);
  float* cis = xn;  // aliases xn: greedy never reads xn, gemm done first
  float* ker = (float*)(ws + 65536 + (size_t)NTOK * DIM * 4);

  hipMemsetAsync(d_ws, 0, 32768, stream);  // zero candidate slots
  k_prep<<<1, 1024, 0, stream>>>(attn, rel);
  k_norm<<<NTOK, 256, 0, stream>>>(feat, xn);
  k_gemm<<<dim3(64, 64), 256, 0, stream>>>(xn, rel, ker);
  k_greedy<<<GB, GT, 0, stream>>>(ker, feat, out, cis, slots);
}